// Round 1
// 367.336 us; speedup vs baseline: 1.0227x; 1.0227x over previous
//
#include <hip/hip_runtime.h>
#include <math.h>

#define Bn 64
#define Tn 2048
#define ENC 512
#define ATT 128
#define RNN 1024
#define NF 32
#define KS 31
#define WINR 32
#define WSZ 65          // window positions: 2*WINR + 1
#define HALO 95         // WSZ + KS - 1
#define NTH 512

// Fully fused: everything outside the 65-wide window has softmax weight
// exactly 0 (exp(-1e9 - m) underflows in fp32). One block per batch.
// The context window of `memory` (133 KB) is prefetched into registers
// (33 float2/thread) in the same streaming pass as the pmem/hidden staging.
// This revision: (a) qproj reads of qw are wave-coalesced (lanes read a
// contiguous 1 KB per instruction instead of 64 scattered 64-B lines),
// (b) softmax + new_pos are wave-parallel butterflies instead of 65/1-thread
// serial loops, (c) the mostly-zero attention_weights row is zero-stored in
// the staging phase and only the 65 window values are patched after softmax.
__global__ __launch_bounds__(NTH)
void attn_fused(
    const float* __restrict__ hidden,        // [B, RNN]
    const float* __restrict__ memory,        // [B, T, ENC]
    const float* __restrict__ pmem,          // [B, T, ATT]
    const float* __restrict__ cat,           // [B, 2, T]
    const unsigned char* __restrict__ mask,  // [B, T] bool
    const int*  __restrict__ mlen,           // [B]
    const float* __restrict__ cpos,          // [B]
    const float* __restrict__ convw,         // [NF, 2, KS]
    const float* __restrict__ densew,        // [ATT, NF]
    const float* __restrict__ qw,            // [ATT, RNN]
    const float* __restrict__ vw,            // [1, ATT]
    const float* __restrict__ posoff,        // [1]
    float* __restrict__ out)                 // ctx[B*ENC] | w[B*T] | newpos[B]
{
    __shared__ float s_hidden[RNN];          // 4 KB
    __shared__ float s_qproj[ATT];
    __shared__ float s_ldw[ATT * 33];        // densew padded -> conflict-free
    __shared__ float s_cw[NF * 2 * KS];
    __shared__ float s_cat[2 * HALO];
    __shared__ float s_conv[WSZ * NF];
    __shared__ float s_pm[WSZ * ATT];        // 33 KB pmem window
    __shared__ unsigned char s_mk[WSZ];
    __shared__ float s_align[WSZ];
    __shared__ float s_w[WSZ];
    __shared__ float2 s_red[2 * (ENC / 2)]; // 4 KB ctx partials

    const int b = blockIdx.x;
    const int tid = threadIdx.x;
    const int lane = tid & 63;
    const int wv = tid >> 6;

    // ---- window start (uniform scalar; rintf == np.round half-even) ----
    float cp = cpos[b] + posoff[0];
    float mend = (float)(mlen[b] - 1 - WINR);
    cp = fminf(fmaxf(cp, (float)WINR), mend);
    int s = (int)rintf(fmaxf(cp - (float)WINR, 0.0f));
    if (s < 0) s = 0;
    if (s > Tn - WSZ) s = Tn - WSZ;          // defensive; unreachable normally

    // ---- stage small inputs to LDS (independent loads -> pipelined) ----
    for (int i = tid; i < RNN / 4; i += NTH)
        ((float4*)s_hidden)[i] = ((const float4*)(hidden + (size_t)b * RNN))[i];
    {   // pmem window: one contiguous 8320-float span, 512B-aligned base
        const float4* pmw = (const float4*)(pmem + ((size_t)b * Tn + s) * ATT);
        for (int i = tid; i < WSZ * ATT / 4; i += NTH)
            ((float4*)s_pm)[i] = pmw[i];
    }
    for (int i = tid; i < ATT * NF; i += NTH) {
        int a = i >> 5, f = i & 31;
        s_ldw[a * 33 + f] = densew[i];
    }
    for (int i = tid; i < NF * 2 * KS; i += NTH) s_cw[i] = convw[i];
    for (int i = tid; i < 2 * HALO; i += NTH) {
        int cch = i / HALO, j = i - cch * HALO;
        int t = s - (KS - 1) / 2 + j;
        float v = 0.0f;
        if (t >= 0 && t < Tn) v = cat[((size_t)b * 2 + cch) * Tn + t];
        s_cat[cch * HALO + j] = v;
    }
    if (tid < WSZ) s_mk[tid] = mask[(size_t)b * Tn + s + tid];

    // v_w held in registers from the start (2 VGPRs, issued with staging)
    const float va0 = vw[lane];
    const float va1 = vw[lane + 64];

    // ---- context-window prefetch into registers (consumed last) ----
    // thread -> enc float2 index c = tid&255, row group g = tid>>8 (wave-uniform)
    const int c = tid & 255;
    const int g = tid >> 8;
    float2 v[33];
    const float2* m2 = (const float2*)(memory + (size_t)b * Tn * ENC)
                       + (size_t)(s + g) * (ENC / 2) + c;
#pragma unroll
    for (int i = 0; i < 33; i++) {
        int j = g + 2 * i;
        if (j < WSZ) v[i] = m2[(size_t)(2 * i) * (ENC / 2)];
    }

    // ---- zero the attention_weights row now (window patched post-softmax) ----
    {
        float4 z = make_float4(0.0f, 0.0f, 0.0f, 0.0f);
        float4* wout = (float4*)(out + (size_t)Bn * ENC + (size_t)b * Tn);
        for (int i = tid; i < Tn / 4; i += NTH) wout[i] = z;
    }
    __syncthreads();

    // ---- query projection: wave wv owns a = wv*16 + r, coalesced qw reads ----
    // lane holds hidden[lane*4 + p*256 .. +3] for p=0..3 (16 floats, 16 VGPRs);
    // each global_load_dwordx4 covers a contiguous 1 KB of qw across the wave.
    {
        const float4* h4 = (const float4*)s_hidden;
        const float4 h0 = h4[lane];
        const float4 h1 = h4[64 + lane];
        const float4 h2 = h4[128 + lane];
        const float4 h3 = h4[192 + lane];
#pragma unroll 4
        for (int r = 0; r < 16; r++) {
            const int a = (wv << 4) + r;
            const float4* qa = (const float4*)qw + (size_t)a * (RNN / 4);
            float4 q0 = qa[lane];
            float4 q1 = qa[64 + lane];
            float4 q2 = qa[128 + lane];
            float4 q3 = qa[192 + lane];
            float acc = q0.x * h0.x + q0.y * h0.y + q0.z * h0.z + q0.w * h0.w
                      + q1.x * h1.x + q1.y * h1.y + q1.z * h1.z + q1.w * h1.w
                      + q2.x * h2.x + q2.y * h2.y + q2.z * h2.z + q2.w * h2.w
                      + q3.x * h3.x + q3.y * h3.y + q3.z * h3.z + q3.w * h3.w;
#pragma unroll
            for (int off = 32; off > 0; off >>= 1) acc += __shfl_xor(acc, off);
            if (lane == 0) s_qproj[a] = acc;
        }
    }

    // ---- location conv over window: 65*32 tasks (doesn't touch s_qproj) ----
    for (int i = tid; i < WSZ * NF; i += NTH) {
        int j = i >> 5, f = i & 31;
        const float* w0 = s_cw + f * 2 * KS;
        const float* c0 = s_cat + j;
        const float* c1 = s_cat + HALO + j;
        float acc = 0.0f;
#pragma unroll
        for (int k = 0; k < KS; k++) acc += c0[k] * w0[k] + c1[k] * w0[KS + k];
        s_conv[i] = acc;
    }
    __syncthreads();

    // ---- alignment[j]: one wave per j, lanes cover dims (lane, lane+64) ----
    for (int j = wv; j < WSZ; j += 8) {
        const float* pmr = s_pm + j * ATT;
        const float* cv = s_conv + j * NF;
        const float* l0 = s_ldw + lane * 33;
        const float* l1 = s_ldw + (lane + 64) * 33;
        float x0 = s_qproj[lane] + pmr[lane];
        float x1 = s_qproj[lane + 64] + pmr[lane + 64];
#pragma unroll
        for (int f = 0; f < NF; f++) {
            float cc = cv[f];
            x0 += cc * l0[f];
            x1 += cc * l1[f];
        }
        float val = tanhf(x0) * va0 + tanhf(x1) * va1;
        for (int off = 32; off > 0; off >>= 1) val += __shfl_down(val, off);
        if (lane == 0) s_align[j] = s_mk[j] ? -1e9f : val;
    }
    __syncthreads();

    // ---- softmax over the 65-wide window: wave 0, butterfly reduce ----
    if (wv == 0) {
        float a0 = s_align[lane];
        float aex = (lane == 0) ? s_align[64] : -1e30f;
        float m = fmaxf(a0, aex);
#pragma unroll
        for (int off = 32; off > 0; off >>= 1) m = fmaxf(m, __shfl_xor(m, off));
        float e0 = expf(a0 - m);
        float e64 = (lane == 0) ? expf(s_align[64] - m) : 0.0f;
        float t = e0 + e64;
#pragma unroll
        for (int off = 32; off > 0; off >>= 1) t += __shfl_xor(t, off);
        s_w[lane] = e0 / t;
        if (lane == 0) s_w[64] = e64 / t;
    }
    __syncthreads();

    // ---- patch the 65 window weights (row zeros already stored) ----
    if (tid < WSZ)
        out[(size_t)Bn * ENC + (size_t)b * Tn + s + tid] = s_w[tid];

    // ---- new_pos: wave 1 butterfly (concurrent with patch + context) ----
    if (wv == 1) {
        float np = s_w[lane] * (float)(s + lane);
        if (lane == 0) np += s_w[64] * (float)(s + 64);
#pragma unroll
        for (int off = 32; off > 0; off >>= 1) np += __shfl_xor(np, off);
        if (lane == 0) out[(size_t)Bn * ENC + (size_t)Bn * Tn + b] = np;
    }

    // ---- context finalize: weighted sum of the prefetched registers ----
    {
        float2 acc = make_float2(0.0f, 0.0f);
#pragma unroll
        for (int i = 0; i < 33; i++) {
            int j = g + 2 * i;
            if (j < WSZ) {
                float wj = s_w[j];
                acc.x += wj * v[i].x;
                acc.y += wj * v[i].y;
            }
        }
        s_red[g * (ENC / 2) + c] = acc;
    }
    __syncthreads();
    if (tid < ENC / 2) {
        float2 a = s_red[tid], bb = s_red[(ENC / 2) + tid];
        float2 r = make_float2(a.x + bb.x, a.y + bb.y);
        ((float2*)out)[(size_t)b * (ENC / 2) + tid] = r;
    }
}

extern "C" void kernel_launch(void* const* d_in, const int* in_sizes, int n_in,
                              void* d_out, int out_size, void* d_ws, size_t ws_size,
                              hipStream_t stream) {
    attn_fused<<<Bn, NTH, 0, stream>>>(
        (const float*)d_in[0],          // attention_hidden_state
        (const float*)d_in[1],          // memory
        (const float*)d_in[2],          // processed_memory
        (const float*)d_in[3],          // attention_weights_cat
        (const unsigned char*)d_in[4],  // mask (bool)
        (const int*)d_in[5],            // memory_lengths
        (const float*)d_in[6],          // current_pos
        (const float*)d_in[7],          // loc_conv_w
        (const float*)d_in[8],          // loc_dense_w
        (const float*)d_in[9],          // query_w
        (const float*)d_in[10],         // v_w
        (const float*)d_in[11],         // pos_offset
        (float*)d_out);
}